// Round 15
// baseline (293.324 us; speedup 1.0000x reference)
//
#include <hip/hip_runtime.h>
#include <hip/hip_bf16.h>

typedef short bf16x8 __attribute__((ext_vector_type(8)));
typedef float f32x4 __attribute__((ext_vector_type(4)));

// B=4, N=M=2048, D=512, H=8, C=64; combined head dim = 128 (q|p, k|r)

__device__ __forceinline__ unsigned short f2bf(float f) {
  union { __hip_bfloat16 h; unsigned short u; } v;
  v.h = __float2bfloat16(f);
  return v.u;
}

__device__ __forceinline__ unsigned pk2(float a, float b) {
  union { __hip_bfloat162 h; unsigned u; } v;
  v.h = __float22bfloat162_rn(float2{a, b});
  return v.u;  // low 16 = bf16(a)
}

__device__ __forceinline__ float fexp2(float x) {
#if __has_builtin(__builtin_amdgcn_exp2f)
  return __builtin_amdgcn_exp2f(x);
#else
  return exp2f(x);
#endif
}

// ---------- weight transpose: W fp32 [K=512][D=512] -> WT bf16 [D][K] ----------
__global__ __launch_bounds__(256) void wt_kernel(
    const float* __restrict__ W0, const float* __restrict__ W1,
    const float* __restrict__ W2, const float* __restrict__ W3,
    unsigned short* __restrict__ T0, unsigned short* __restrict__ T1,
    unsigned short* __restrict__ T2, unsigned short* __restrict__ T3)
{
  __shared__ float t[32][33];
  const float* W; unsigned short* T;
  switch (blockIdx.z) {
    case 0: W = W0; T = T0; break;
    case 1: W = W1; T = T1; break;
    case 2: W = W2; T = T2; break;
    default: W = W3; T = T3; break;
  }
  int k0 = blockIdx.x * 32, d0 = blockIdx.y * 32;
  int tx = threadIdx.x, ty = threadIdx.y;
#pragma unroll
  for (int i = 0; i < 4; i++)
    t[ty + 8 * i][tx] = W[(size_t)(k0 + ty + 8 * i) * 512 + d0 + tx];
  __syncthreads();
#pragma unroll
  for (int i = 0; i < 4; i++)
    T[(size_t)(d0 + ty + 8 * i) * 512 + k0 + tx] = f2bf(t[tx][ty + 8 * i]);
}

// ---------- GEMM staging (512 threads): into LDS bf16 stride 72 (2-way free) ----------
__device__ __forceinline__ void stage256_f32(short* dst, const float* __restrict__ src,
                                             int row0, int kk, int tid) {
#pragma unroll
  for (int it = 0; it < 8; it++) {
    int idx = tid + 512 * it;           // 4096 float4s: 256 rows x 64 k
    int r = idx >> 4, c4 = (idx & 15) << 2;
    float4 v = *(const float4*)&src[(size_t)(row0 + r) * 512 + kk + c4];
    uint2 pk = {pk2(v.x, v.y), pk2(v.z, v.w)};
    *(uint2*)&dst[r * 72 + c4] = pk;
  }
}

__device__ __forceinline__ void stage128_f32(short* dst, const float* __restrict__ src,
                                             int row0, int kk, int tid) {
#pragma unroll
  for (int it = 0; it < 4; it++) {
    int idx = tid + 512 * it;           // 2048 float4s: 128 rows x 64 k
    int r = idx >> 4, c4 = (idx & 15) << 2;
    float4 v = *(const float4*)&src[(size_t)(row0 + r) * 512 + kk + c4];
    uint2 pk = {pk2(v.x, v.y), pk2(v.z, v.w)};
    *(uint2*)&dst[r * 72 + c4] = pk;
  }
}

__device__ __forceinline__ void stage256_bf16(short* dst, const unsigned short* __restrict__ src,
                                              int row0, int kk, int tid) {
#pragma unroll
  for (int it = 0; it < 4; it++) {
    int idx = tid + 512 * it;           // 2048 ushort8s: 256 rows x 64 k
    int r = idx >> 3, c8 = (idx & 7) << 3;
    bf16x8 v = *(const bf16x8*)&src[(size_t)(row0 + r) * 512 + kk + c8];
    *(bf16x8*)&dst[r * 72 + c8] = v;
  }
}

__device__ __forceinline__ void stage128_bf16(short* dst, const unsigned short* __restrict__ src,
                                              int row0, int kk, int tid) {
#pragma unroll
  for (int it = 0; it < 2; it++) {
    int idx = tid + 512 * it;           // 1024 ushort8s: 128 rows x 64 k
    int r = idx >> 3, c8 = (idx & 7) << 3;
    bf16x8 v = *(const bf16x8*)&src[(size_t)(row0 + r) * 512 + kk + c8];
    *(bf16x8*)&dst[r * 72 + c8] = v;
  }
}

__device__ __forceinline__ void mfma_step64(const short* As, const short* Bs,
                                            f32x4 acc[4][4], int lane, int wr, int wc) {
  int rb = lane & 15, g8 = (lane >> 4) * 8;
#pragma unroll
  for (int ks = 0; ks < 64; ks += 32) {
    bf16x8 af[4], bfv[4];
#pragma unroll
    for (int t = 0; t < 4; t++) {
      af[t]  = *(const bf16x8*)&As[(wr * 64 + t * 16 + rb) * 72 + ks + g8];
      bfv[t] = *(const bf16x8*)&Bs[(wc * 64 + t * 16 + rb) * 72 + ks + g8];
    }
#pragma unroll
    for (int tm = 0; tm < 4; tm++)
#pragma unroll
      for (int tn = 0; tn < 4; tn++)
        acc[tm][tn] = __builtin_amdgcn_mfma_f32_16x16x32_bf16(af[tm], bfv[tn], acc[tm][tn], 0, 0, 0);
  }
}

// ---------- merged projections, 256x128 tile, 512 threads (8 waves = 4x2) ----------
// blocks 0..511: z = bid>>7, r = bid&127, bj = r&3 (fastest -> A-tile L2 reuse), bi = r>>2
// blocks 512..639: V projection; r = bid-512, bi = r&1 (fastest -> iv-tile reuse), bj = r>>1
__global__ __launch_bounds__(512, 4) void gemm_all(
    const float* __restrict__ iq, const float* __restrict__ eq,
    const float* __restrict__ ik, const float* __restrict__ ek,
    const float* __restrict__ iv,
    const unsigned short* __restrict__ WTq, const unsigned short* __restrict__ WTk,
    const unsigned short* __restrict__ WTp, const unsigned short* __restrict__ WTv,
    const float* __restrict__ bq, const float* __restrict__ bk,
    const float* __restrict__ bp, const float* __restrict__ bv,
    unsigned short* __restrict__ QC, unsigned short* __restrict__ KC,
    unsigned short* __restrict__ VT)
{
  __shared__ short As[256 * 72];   // 36.9 KB
  __shared__ short Bs[128 * 72];   // 18.4 KB
  int tid = threadIdx.x, lane = tid & 63, w = tid >> 6;
  int wr = w >> 1, wc = w & 1;     // 4x2 wave grid, wave tile 64x64
  int g = lane >> 4, c = lane & 15;
  int bid = blockIdx.x;
  f32x4 acc[4][4];
#pragma unroll
  for (int i = 0; i < 4; i++)
#pragma unroll
    for (int j = 0; j < 4; j++) acc[i][j] = (f32x4){0.f, 0.f, 0.f, 0.f};

  if (bid < 512) {
    int z = bid >> 7, r = bid & 127;
    int bj = r & 3, bi = r >> 2;
    const float* A; const unsigned short* WT; const float* bias; unsigned short* out; int ooff;
    switch (z) {
      case 0: A = iq; WT = WTq; bias = bq; out = QC; ooff = 0;  break;
      case 1: A = eq; WT = WTp; bias = bp; out = QC; ooff = 64; break;
      case 2: A = ik; WT = WTk; bias = bk; out = KC; ooff = 0;  break;
      default: A = ek; WT = WTp; bias = bp; out = KC; ooff = 64; break;
    }
    for (int kk = 0; kk < 512; kk += 64) {
      __syncthreads();
      stage256_f32(As, A, bi * 256, kk, tid);
      stage128_bf16(Bs, WT, bj * 128, kk, tid);
      __syncthreads();
      mfma_step64(As, Bs, acc, lane, wr, wc);
    }
#pragma unroll
    for (int tm = 0; tm < 4; tm++) {
#pragma unroll
      for (int tn = 0; tn < 4; tn++) {
        int dcol = bj * 128 + wc * 64 + tn * 16 + c;
        float bvv = bias[dcol];
        int h = dcol >> 6, cc = dcol & 63;
#pragma unroll
        for (int j = 0; j < 4; j++) {
          int i = bi * 256 + wr * 64 + tm * 16 + 4 * g + j;  // global row = b*2048+n
          int b = i >> 11, n = i & 2047;
          out[((size_t)(b * 8 + h) * 2048 + n) * 128 + cc + ooff] = f2bf(acc[tm][tn][j] + bvv);
        }
      }
    }
  } else {
    // V projection, transposed output: VT[B][H][64][M]
    int r = bid - 512;
    int bi = r & 1, bj = r >> 1;    // bi fastest: 2 d-tiles share one iv-tile
    for (int kk = 0; kk < 512; kk += 64) {
      __syncthreads();
      stage256_bf16(As, WTv, bi * 256, kk, tid);  // rows = d
      stage128_f32(Bs, iv, bj * 128, kk, tid);    // rows = s
      __syncthreads();
      mfma_step64(As, Bs, acc, lane, wr, wc);
    }
#pragma unroll
    for (int tm = 0; tm < 4; tm++) {
#pragma unroll
      for (int tn = 0; tn < 4; tn++) {
#pragma unroll
        for (int j = 0; j < 4; j++) {
          int i  = bi * 256 + wr * 64 + tm * 16 + 4 * g + j;  // d
          int jj = bj * 128 + wc * 64 + tn * 16 + c;          // s = b*2048+m
          int b = jj >> 11, m = jj & 2047;
          int h = i >> 6, cc = i & 63;
          VT[((size_t)(b * 8 + h) * 64 + cc) * 2048 + m] = f2bf(acc[tm][tn][j] + bv[i]);
        }
      }
    }
  }
}

// ---------- fused attention (R14, best measured 281.0 us) ----------
// pass A: K/V LDS-staged (32-m chunks), double-buffered; swapped QK^T; PV; combine.
// pass B: K LDS-staged in 64-m chunks (Kbuf2 aliases dead Vbuf/Plds) -> half the
//         barriers, 2x MFMA + 2x stores per round. sums_lds in non-overlapped tail.
__global__ __launch_bounds__(512, 4) void attn_kernel(
    const unsigned short* __restrict__ QC, const unsigned short* __restrict__ KC,
    const unsigned short* __restrict__ VT, float* __restrict__ out)
{
  // LDS pool (76800 B): [0) KbufA 34816 | [17408s) Vbuf 20480 | [27648s) Plds 20480 | [37888s) sums 1024
  // pass B: Kbuf2 = pool[0 .. 34816 shorts) = 69632 B (overlays KbufA+Vbuf+Plds; sums untouched)
  __shared__ __align__(16) short pool[38400];
  short* KbufA = pool;                      // [half][dbuf][32*136]
  short* VbufA = pool + 17408;              // [half][dbuf][64*40]
  short* PldsA = pool + 27648;              // [w][32*40]
  float* sums_lds = (float*)(pool + 37888); // [8][32]

  const int tid = threadIdx.x;
  const int lane = tid & 63, w = tid >> 6;
  const int g = lane >> 4, c = lane & 15;
  const int qw = w & 3, half = w >> 2;

  // XCD swizzle: 64 consecutive blocks (4 bh) per XCD -> K/V L2-resident
  const int lin = blockIdx.x;             // 512 blocks
  const int swz = (lin & 7) * 64 + (lin >> 3);
  const int qb = swz & 15, bh = swz >> 4;
  const int b = bh >> 3, h = bh & 7;

  const unsigned short* Qp = QC + (size_t)bh * 2048 * 128;
  const unsigned short* Kp = KC + (size_t)bh * 2048 * 128;
  const unsigned short* Vp = VT + (size_t)bh * 64 * 2048;
  float* hidOut = out;
  float* attnOut = out + (size_t)4 * 2048 * 512;

  const int qbase = qb * 128 + qw * 32;
  const int m0 = half * 1024;
  const float SC = 0.125f * 1.4426950408889634f;  // log2(e)/sqrt(C)

  // cooperative staging roles: 256 threads per half
  const int tt = tid & 255, sthalf = tid >> 8;
  const int krow = tt >> 3, ku = tt & 7;    // pass A K: 32 rows x 2x16B per thread
  const int vrow = tt >> 2, vu = tt & 3;    // pass A V: 64 rows x 1x16B per thread
  const int krow2 = tt >> 2, ku2 = tt & 3;  // pass B K: 64 rows x 4x16B per thread
  const int smb = sthalf * 1024;

  bf16x8 kr0, kr1, vr;
  auto K_ISSUE = [&](int ch) {
    const unsigned short* src = &Kp[(size_t)(smb + ch * 32 + krow) * 128];
    kr0 = *(const bf16x8*)&src[ku * 8];
    kr1 = *(const bf16x8*)&src[(ku + 8) * 8];
  };
  auto V_ISSUE = [&](int ch) {
    vr = *(const bf16x8*)&Vp[(size_t)vrow * 2048 + smb + ch * 32 + vu * 8];
  };
  auto K_WRITE = [&](int buf) {
    short* d = &KbufA[(sthalf * 2 + buf) * (32 * 136) + krow * 136];
    *(bf16x8*)&d[ku * 8] = kr0;
    *(bf16x8*)&d[(ku + 8) * 8] = kr1;
  };
  auto V_WRITE = [&](int buf) {
    *(bf16x8*)&VbufA[(sthalf * 2 + buf) * (64 * 40) + vrow * 40 + vu * 8] = vr;
  };

  bf16x8 kr2[4];
  auto K_ISSUE2 = [&](int ch) {
    const unsigned short* src = &Kp[(size_t)(smb + ch * 64 + krow2) * 128 + ku2 * 32];
#pragma unroll
    for (int i = 0; i < 4; i++) kr2[i] = *(const bf16x8*)&src[i * 8];
  };
  auto K_WRITE2 = [&](int buf) {
    short* d = &pool[(sthalf * 2 + buf) * (64 * 136) + krow2 * 136 + ku2 * 32];
#pragma unroll
    for (int i = 0; i < 4; i++) *(bf16x8*)&d[i * 8] = kr2[i];
  };

  // Q fragments resident for both passes (32 rows x 128 k)
  bf16x8 qf[2][4];
#pragma unroll
  for (int qt = 0; qt < 2; qt++)
#pragma unroll
    for (int kc = 0; kc < 4; kc++)
      qf[qt][kc] = *(const bf16x8*)&Qp[(size_t)(qbase + qt * 16 + c) * 128 + kc * 32 + 8 * g];

  float sums[2] = {0.f, 0.f};   // per-lane: q column = qt*16 + c
  f32x4 hid[2][4];
#pragma unroll
  for (int qt = 0; qt < 2; qt++)
#pragma unroll
    for (int ct = 0; ct < 4; ct++) hid[qt][ct] = (f32x4){0.f, 0.f, 0.f, 0.f};
  short* myP = &PldsA[w * (32 * 40)];

  // ---- pass A: partial row sums + partial hidden over this wave's 1024-m half ----
  K_ISSUE(0); V_ISSUE(0);
  K_WRITE(0); V_WRITE(0);
  __syncthreads();
  for (int ch = 0; ch < 32; ch++) {
    const int buf = ch & 1;
    if (ch < 31) { K_ISSUE(ch + 1); V_ISSUE(ch + 1); }  // prefetch under compute

    const short* Kl = &KbufA[(half * 2 + buf) * (32 * 136)];
    const short* Vl = &VbufA[(half * 2 + buf) * (64 * 40)];
#pragma unroll
    for (int mt = 0; mt < 2; mt++) {
      bf16x8 kf[4];
#pragma unroll
      for (int kc = 0; kc < 4; kc++)
        kf[kc] = *(const bf16x8*)&Kl[(mt * 16 + c) * 136 + kc * 32 + 8 * g];
#pragma unroll
      for (int qt = 0; qt < 2; qt++) {
        // SWAPPED: D[m][q], m = mt*16 + 4g + j, q = qt*16 + c
        f32x4 s = {0.f, 0.f, 0.f, 0.f};
#pragma unroll
        for (int kc = 0; kc < 4; kc++)
          s = __builtin_amdgcn_mfma_f32_16x16x32_bf16(kf[kc], qf[qt][kc], s, 0, 0, 0);
        float p0 = fexp2(s[0] * SC), p1 = fexp2(s[1] * SC);
        float p2 = fexp2(s[2] * SC), p3 = fexp2(s[3] * SC);
        sums[qt] += (p0 + p1) + (p2 + p3);
        uint2 pk = {pk2(p0, p1), pk2(p2, p3)};
        *(uint2*)&myP[(qt * 16 + c) * 40 + mt * 16 + 4 * g] = pk;  // P[q][m], b64
      }
    }
    asm volatile("s_waitcnt lgkmcnt(0)" ::: "memory");  // P write->read handoff
    bf16x8 pf[2], vf[4];
#pragma unroll
    for (int qt = 0; qt < 2; qt++)
      pf[qt] = *(const bf16x8*)&myP[(qt * 16 + c) * 40 + 8 * g];
#pragma unroll
    for (int ct = 0; ct < 4; ct++)
      vf[ct] = *(const bf16x8*)&Vl[(ct * 16 + c) * 40 + 8 * g];
#pragma unroll
    for (int qt = 0; qt < 2; qt++)
#pragma unroll
      for (int ct = 0; ct < 4; ct++)
        hid[qt][ct] = __builtin_amdgcn_mfma_f32_16x16x32_bf16(pf[qt], vf[ct], hid[qt][ct], 0, 0, 0);

    if (ch < 31) { K_WRITE(buf ^ 1); V_WRITE(buf ^ 1); }
    __syncthreads();
  }

  // ---- in-block combine: sums via LDS; hidden partials via dead KbufA ----
#pragma unroll
  for (int qt = 0; qt < 2; qt++) {
    float s = sums[qt];
    s += __shfl_xor(s, 16);
    s += __shfl_xor(s, 32);
    if (g == 0) sums_lds[w * 32 + qt * 16 + c] = s;
  }
  float* hidx = (float*)pool;   // 32 KB scratch (KbufA region, dead here)
  if (half == 1) {
#pragma unroll
    for (int qt = 0; qt < 2; qt++)
#pragma unroll
      for (int ct = 0; ct < 4; ct++)
#pragma unroll
        for (int j = 0; j < 4; j++)
          hidx[(qw * 32 + qt * 16 + 4 * g + j) * 64 + ct * 16 + c] = hid[qt][ct][j];
  }
  __syncthreads();

  // hidden write (unswapped PV layout): q = qt*16 + 4g + j
  if (half == 0) {
#pragma unroll
    for (int qt = 0; qt < 2; qt++)
#pragma unroll
      for (int ct = 0; ct < 4; ct++)
#pragma unroll
        for (int j = 0; j < 4; j++) {
          int row = qt * 16 + 4 * g + j;
          float rcv = 1.0f / (sums_lds[qw * 32 + row] + sums_lds[(qw + 4) * 32 + row]);
          int q = qbase + row;
          float v = hid[qt][ct][j] + hidx[(qw * 32 + row) * 64 + ct * 16 + c];
          hidOut[((size_t)b * 2048 + q) * 512 + h * 64 + ct * 16 + c] = v * rcv;
        }
  }

  // recip for pass B's swapped layout: lane owns q = qt*16 + c (uniform in g)
  float rcB[2];
#pragma unroll
  for (int qt = 0; qt < 2; qt++)
    rcB[qt] = 1.0f / (sums_lds[qw * 32 + qt * 16 + c] + sums_lds[(qw + 4) * 32 + qt * 16 + c]);
  __syncthreads();  // hidx reads done before pass-B staging overwrites the pool

  // ---- pass B: staged K in 64-m chunks (Kbuf2 overlay), swapped MFMA, float4 stores ----
  K_ISSUE2(0); K_WRITE2(0);
  __syncthreads();
  for (int ch = 0; ch < 16; ch++) {
    const int buf = ch & 1;
    if (ch < 15) K_ISSUE2(ch + 1);

    const short* Kl = &pool[(half * 2 + buf) * (64 * 136)];
    const int mbase = m0 + ch * 64;
#pragma unroll
    for (int mt = 0; mt < 4; mt++) {
      bf16x8 kf[4];
#pragma unroll
      for (int kc = 0; kc < 4; kc++)
        kf[kc] = *(const bf16x8*)&Kl[(mt * 16 + c) * 136 + kc * 32 + 8 * g];
#pragma unroll
      for (int qt = 0; qt < 2; qt++) {
        // SWAPPED: D[m][q]; lane gets m = mt*16 + 4g + j for q = qt*16 + c
        f32x4 s = {0.f, 0.f, 0.f, 0.f};
#pragma unroll
        for (int kc = 0; kc < 4; kc++)
          s = __builtin_amdgcn_mfma_f32_16x16x32_bf16(kf[kc], qf[qt][kc], s, 0, 0, 0);
        float4 o = {fexp2(s[0] * SC) * rcB[qt], fexp2(s[1] * SC) * rcB[qt],
                    fexp2(s[2] * SC) * rcB[qt], fexp2(s[3] * SC) * rcB[qt]};
        *(float4*)&attnOut[((size_t)bh * 2048 + qbase + qt * 16 + c) * 2048
                           + mbase + mt * 16 + 4 * g] = o;
      }
    }

    if (ch < 15) K_WRITE2(buf ^ 1);
    __syncthreads();
  }
}

extern "C" void kernel_launch(void* const* d_in, const int* in_sizes, int n_in,
                              void* d_out, int out_size, void* d_ws, size_t ws_size,
                              hipStream_t stream) {
  const float* input_q = (const float*)d_in[0];
  const float* input_k = (const float*)d_in[1];
  const float* input_v = (const float*)d_in[2];
  const float* embed_q = (const float*)d_in[3];
  const float* embed_k = (const float*)d_in[4];
  const float* Wq = (const float*)d_in[5];
  const float* bq = (const float*)d_in[6];
  const float* Wk = (const float*)d_in[7];
  const float* bk = (const float*)d_in[8];
  const float* Wv = (const float*)d_in[9];
  const float* bv = (const float*)d_in[10];
  const float* Wp = (const float*)d_in[11];
  const float* bp = (const float*)d_in[12];

  // workspace layout (bf16 elements): QC 16MB | KC 16MB | VT 8MB | 4x WT 2MB  (~42MB)
  unsigned short* ws = (unsigned short*)d_ws;
  unsigned short* QC  = ws;
  unsigned short* KC  = QC + (size_t)32 * 2048 * 128;
  unsigned short* VT  = KC + (size_t)32 * 2048 * 128;
  unsigned short* WTq = VT + (size_t)32 * 64 * 2048;
  unsigned short* WTk = WTq + 512 * 512;
  unsigned short* WTv = WTk + 512 * 512;
  unsigned short* WTp = WTv + 512 * 512;

  wt_kernel<<<dim3(16, 16, 4), dim3(32, 8), 0, stream>>>(Wq, Wk, Wv, Wp, WTq, WTk, WTv, WTp);
  gemm_all<<<dim3(640), 512, 0, stream>>>(input_q, embed_q, input_k, embed_k, input_v,
                                          WTq, WTk, WTp, WTv, bq, bk, bp, bv, QC, KC, VT);
  attn_kernel<<<dim3(512), 512, 0, stream>>>(QC, KC, VT, (float*)d_out);
}

// Round 16
// 282.706 us; speedup vs baseline: 1.0376x; 1.0376x over previous
//
#include <hip/hip_runtime.h>
#include <hip/hip_bf16.h>

typedef short bf16x8 __attribute__((ext_vector_type(8)));
typedef float f32x4 __attribute__((ext_vector_type(4)));

// B=4, N=M=2048, D=512, H=8, C=64; combined head dim = 128 (q|p, k|r)

__device__ __forceinline__ unsigned short f2bf(float f) {
  union { __hip_bfloat16 h; unsigned short u; } v;
  v.h = __float2bfloat16(f);
  return v.u;
}

__device__ __forceinline__ unsigned pk2(float a, float b) {
  union { __hip_bfloat162 h; unsigned u; } v;
  v.h = __float22bfloat162_rn(float2{a, b});
  return v.u;  // low 16 = bf16(a)
}

__device__ __forceinline__ float fexp2(float x) {
#if __has_builtin(__builtin_amdgcn_exp2f)
  return __builtin_amdgcn_exp2f(x);
#else
  return exp2f(x);
#endif
}

// ---------- weight transpose: W fp32 [K=512][D=512] -> WT bf16 [D][K] ----------
__global__ __launch_bounds__(256) void wt_kernel(
    const float* __restrict__ W0, const float* __restrict__ W1,
    const float* __restrict__ W2, const float* __restrict__ W3,
    unsigned short* __restrict__ T0, unsigned short* __restrict__ T1,
    unsigned short* __restrict__ T2, unsigned short* __restrict__ T3)
{
  __shared__ float t[32][33];
  const float* W; unsigned short* T;
  switch (blockIdx.z) {
    case 0: W = W0; T = T0; break;
    case 1: W = W1; T = T1; break;
    case 2: W = W2; T = T2; break;
    default: W = W3; T = T3; break;
  }
  int k0 = blockIdx.x * 32, d0 = blockIdx.y * 32;
  int tx = threadIdx.x, ty = threadIdx.y;
#pragma unroll
  for (int i = 0; i < 4; i++)
    t[ty + 8 * i][tx] = W[(size_t)(k0 + ty + 8 * i) * 512 + d0 + tx];
  __syncthreads();
#pragma unroll
  for (int i = 0; i < 4; i++)
    T[(size_t)(d0 + ty + 8 * i) * 512 + k0 + tx] = f2bf(t[tx][ty + 8 * i]);
}

// ---------- merged projections, 128x128 tile, 512 threads (8 waves = 4x2) ----------
// attn-style single-barrier schedule: ISSUE(k+1) -> MFMA(buf) -> WRITE(buf^1) -> barrier.
// LDS double-buffered (74 KB) -> 2 blocks/CU = 16 waves/CU (same as R14's GEMM).
// blocks 0..1023: z = bid>>8, r = bid&255, bj = r&3 (fastest -> A-tile L2 reuse), bi = r>>2
// blocks 1024..1279: V projection; r = bid-1024, bi = r&3 (fastest -> iv-tile reuse), bj = r>>2
__global__ __launch_bounds__(512, 4) void gemm_all(
    const float* __restrict__ iq, const float* __restrict__ eq,
    const float* __restrict__ ik, const float* __restrict__ ek,
    const float* __restrict__ iv,
    const unsigned short* __restrict__ WTq, const unsigned short* __restrict__ WTk,
    const unsigned short* __restrict__ WTp, const unsigned short* __restrict__ WTv,
    const float* __restrict__ bq, const float* __restrict__ bk,
    const float* __restrict__ bp, const float* __restrict__ bv,
    unsigned short* __restrict__ QC, unsigned short* __restrict__ KC,
    unsigned short* __restrict__ VT)
{
  __shared__ short As[2][128 * 72];   // 2 x 18.4 KB
  __shared__ short Bs[2][128 * 72];   // 2 x 18.4 KB  (total 73.7 KB)
  int tid = threadIdx.x, lane = tid & 63, w = tid >> 6;
  int wr = w >> 1, wc = w & 1;        // 4x2 wave grid, wave tile 32x64
  int g = lane >> 4, c = lane & 15;
  int rb = lane & 15, g8 = g * 8;
  int bid = blockIdx.x;

  f32x4 acc[2][4];
#pragma unroll
  for (int i = 0; i < 2; i++)
#pragma unroll
    for (int j = 0; j < 4; j++) acc[i][j] = (f32x4){0.f, 0.f, 0.f, 0.f};

  // staging decomposition (512 threads, 128 rows x 64 k):
  // f32 side: 2048 float4s -> 4/thread; bf16 side: 1024 ushort8s -> 2/thread
  const int fr_r[4] = { (tid + 0) >> 4, (tid + 512) >> 4, (tid + 1024) >> 4, (tid + 1536) >> 4 };
  const int fr_c = (tid & 15) << 2;
  const int br_r[2] = { (tid + 0) >> 3, (tid + 512) >> 3 };
  const int br_c = (tid & 7) << 3;

  float4 fA[4]; bf16x8 bB[2];

  auto MFMA_STEP = [&](int buf) {
#pragma unroll
    for (int ks = 0; ks < 64; ks += 32) {
      bf16x8 af[2], bfv[4];
#pragma unroll
      for (int t = 0; t < 2; t++)
        af[t] = *(const bf16x8*)&As[buf][(wr * 32 + t * 16 + rb) * 72 + ks + g8];
#pragma unroll
      for (int t = 0; t < 4; t++)
        bfv[t] = *(const bf16x8*)&Bs[buf][(wc * 64 + t * 16 + rb) * 72 + ks + g8];
#pragma unroll
      for (int tm = 0; tm < 2; tm++)
#pragma unroll
        for (int tn = 0; tn < 4; tn++)
          acc[tm][tn] = __builtin_amdgcn_mfma_f32_16x16x32_bf16(af[tm], bfv[tn], acc[tm][tn], 0, 0, 0);
    }
  };

  if (bid < 1024) {
    int z = bid >> 8, r = bid & 255;
    int bj = r & 3, bi = r >> 2;
    const float* A; const unsigned short* WT; const float* bias; unsigned short* out; int ooff;
    switch (z) {
      case 0: A = iq; WT = WTq; bias = bq; out = QC; ooff = 0;  break;
      case 1: A = eq; WT = WTp; bias = bp; out = QC; ooff = 64; break;
      case 2: A = ik; WT = WTk; bias = bk; out = KC; ooff = 0;  break;
      default: A = ek; WT = WTp; bias = bp; out = KC; ooff = 64; break;
    }
    const float* Abase = A + (size_t)(bi * 128) * 512;
    const unsigned short* Bbase = WT + (size_t)(bj * 128) * 512;

    auto ISSUE = [&](int k) {
      int kk = k * 64;
#pragma unroll
      for (int it = 0; it < 4; it++)
        fA[it] = *(const float4*)&Abase[(size_t)fr_r[it] * 512 + kk + fr_c];
#pragma unroll
      for (int it = 0; it < 2; it++)
        bB[it] = *(const bf16x8*)&Bbase[(size_t)br_r[it] * 512 + kk + br_c];
    };
    auto WRITE = [&](int buf) {
#pragma unroll
      for (int it = 0; it < 4; it++) {
        uint2 pk = {pk2(fA[it].x, fA[it].y), pk2(fA[it].z, fA[it].w)};
        *(uint2*)&As[buf][fr_r[it] * 72 + fr_c] = pk;
      }
#pragma unroll
      for (int it = 0; it < 2; it++)
        *(bf16x8*)&Bs[buf][br_r[it] * 72 + br_c] = bB[it];
    };

    ISSUE(0); WRITE(0);
    __syncthreads();
    for (int k = 0; k < 8; k++) {
      int buf = k & 1;
      if (k < 7) ISSUE(k + 1);
      MFMA_STEP(buf);
      if (k < 7) WRITE(buf ^ 1);
      __syncthreads();
    }

#pragma unroll
    for (int tm = 0; tm < 2; tm++) {
#pragma unroll
      for (int tn = 0; tn < 4; tn++) {
        int dcol = bj * 128 + wc * 64 + tn * 16 + c;
        float bvv = bias[dcol];
        int h = dcol >> 6, cc = dcol & 63;
#pragma unroll
        for (int j = 0; j < 4; j++) {
          int i = bi * 128 + wr * 32 + tm * 16 + 4 * g + j;  // global row = b*2048+n
          int b = i >> 11, n = i & 2047;
          out[((size_t)(b * 8 + h) * 2048 + n) * 128 + cc + ooff] = f2bf(acc[tm][tn][j] + bvv);
        }
      }
    }
  } else {
    // V projection, transposed output: VT[B][H][64][M]; As=WTv rows d, Bs=iv rows s
    int r = bid - 1024;
    int bi = r & 3, bj = r >> 2;    // bi fastest: 4 d-tiles share one iv-tile
    const unsigned short* Abase = WTv + (size_t)(bi * 128) * 512;
    const float* Bbase = iv + (size_t)(bj * 128) * 512;

    float4 fB[4]; bf16x8 bA[2];
    auto ISSUE = [&](int k) {
      int kk = k * 64;
#pragma unroll
      for (int it = 0; it < 2; it++)
        bA[it] = *(const bf16x8*)&Abase[(size_t)br_r[it] * 512 + kk + br_c];
#pragma unroll
      for (int it = 0; it < 4; it++)
        fB[it] = *(const float4*)&Bbase[(size_t)fr_r[it] * 512 + kk + fr_c];
    };
    auto WRITE = [&](int buf) {
#pragma unroll
      for (int it = 0; it < 2; it++)
        *(bf16x8*)&As[buf][br_r[it] * 72 + br_c] = bA[it];
#pragma unroll
      for (int it = 0; it < 4; it++) {
        uint2 pk = {pk2(fB[it].x, fB[it].y), pk2(fB[it].z, fB[it].w)};
        *(uint2*)&Bs[buf][fr_r[it] * 72 + fr_c] = pk;
      }
    };

    ISSUE(0); WRITE(0);
    __syncthreads();
    for (int k = 0; k < 8; k++) {
      int buf = k & 1;
      if (k < 7) ISSUE(k + 1);
      MFMA_STEP(buf);
      if (k < 7) WRITE(buf ^ 1);
      __syncthreads();
    }

#pragma unroll
    for (int tm = 0; tm < 2; tm++) {
#pragma unroll
      for (int tn = 0; tn < 4; tn++) {
#pragma unroll
        for (int j = 0; j < 4; j++) {
          int i  = bi * 128 + wr * 32 + tm * 16 + 4 * g + j;  // d
          int jj = bj * 128 + wc * 64 + tn * 16 + c;          // s = b*2048+m
          int b = jj >> 11, m = jj & 2047;
          int h = i >> 6, cc = i & 63;
          VT[((size_t)(b * 8 + h) * 64 + cc) * 2048 + m] = f2bf(acc[tm][tn][j] + bv[i]);
        }
      }
    }
  }
}

// ---------- fused attention (R14, best measured 281.0 us) ----------
// pass A: K/V LDS-staged (32-m chunks), double-buffered; swapped QK^T; PV; combine.
// pass B: K LDS-staged in 64-m chunks (Kbuf2 aliases dead Vbuf/Plds) -> half the
//         barriers, 2x MFMA + 2x stores per round. sums_lds in non-overlapped tail.
__global__ __launch_bounds__(512, 4) void attn_kernel(
    const unsigned short* __restrict__ QC, const unsigned short* __restrict__ KC,
    const unsigned short* __restrict__ VT, float* __restrict__ out)
{
  // LDS pool (76800 B): [0) KbufA 34816 | [17408s) Vbuf 20480 | [27648s) Plds 20480 | [37888s) sums 1024
  // pass B: Kbuf2 = pool[0 .. 34816 shorts) = 69632 B (overlays KbufA+Vbuf+Plds; sums untouched)
  __shared__ __align__(16) short pool[38400];
  short* KbufA = pool;                      // [half][dbuf][32*136]
  short* VbufA = pool + 17408;              // [half][dbuf][64*40]
  short* PldsA = pool + 27648;              // [w][32*40]
  float* sums_lds = (float*)(pool + 37888); // [8][32]

  const int tid = threadIdx.x;
  const int lane = tid & 63, w = tid >> 6;
  const int g = lane >> 4, c = lane & 15;
  const int qw = w & 3, half = w >> 2;

  // XCD swizzle: 64 consecutive blocks (4 bh) per XCD -> K/V L2-resident
  const int lin = blockIdx.x;             // 512 blocks
  const int swz = (lin & 7) * 64 + (lin >> 3);
  const int qb = swz & 15, bh = swz >> 4;
  const int b = bh >> 3, h = bh & 7;

  const unsigned short* Qp = QC + (size_t)bh * 2048 * 128;
  const unsigned short* Kp = KC + (size_t)bh * 2048 * 128;
  const unsigned short* Vp = VT + (size_t)bh * 64 * 2048;
  float* hidOut = out;
  float* attnOut = out + (size_t)4 * 2048 * 512;

  const int qbase = qb * 128 + qw * 32;
  const int m0 = half * 1024;
  const float SC = 0.125f * 1.4426950408889634f;  // log2(e)/sqrt(C)

  // cooperative staging roles: 256 threads per half
  const int tt = tid & 255, sthalf = tid >> 8;
  const int krow = tt >> 3, ku = tt & 7;    // pass A K: 32 rows x 2x16B per thread
  const int vrow = tt >> 2, vu = tt & 3;    // pass A V: 64 rows x 1x16B per thread
  const int krow2 = tt >> 2, ku2 = tt & 3;  // pass B K: 64 rows x 4x16B per thread
  const int smb = sthalf * 1024;

  bf16x8 kr0, kr1, vr;
  auto K_ISSUE = [&](int ch) {
    const unsigned short* src = &Kp[(size_t)(smb + ch * 32 + krow) * 128];
    kr0 = *(const bf16x8*)&src[ku * 8];
    kr1 = *(const bf16x8*)&src[(ku + 8) * 8];
  };
  auto V_ISSUE = [&](int ch) {
    vr = *(const bf16x8*)&Vp[(size_t)vrow * 2048 + smb + ch * 32 + vu * 8];
  };
  auto K_WRITE = [&](int buf) {
    short* d = &KbufA[(sthalf * 2 + buf) * (32 * 136) + krow * 136];
    *(bf16x8*)&d[ku * 8] = kr0;
    *(bf16x8*)&d[(ku + 8) * 8] = kr1;
  };
  auto V_WRITE = [&](int buf) {
    *(bf16x8*)&VbufA[(sthalf * 2 + buf) * (64 * 40) + vrow * 40 + vu * 8] = vr;
  };

  bf16x8 kr2[4];
  auto K_ISSUE2 = [&](int ch) {
    const unsigned short* src = &Kp[(size_t)(smb + ch * 64 + krow2) * 128 + ku2 * 32];
#pragma unroll
    for (int i = 0; i < 4; i++) kr2[i] = *(const bf16x8*)&src[i * 8];
  };
  auto K_WRITE2 = [&](int buf) {
    short* d = &pool[(sthalf * 2 + buf) * (64 * 136) + krow2 * 136 + ku2 * 32];
#pragma unroll
    for (int i = 0; i < 4; i++) *(bf16x8*)&d[i * 8] = kr2[i];
  };

  // Q fragments resident for both passes (32 rows x 128 k)
  bf16x8 qf[2][4];
#pragma unroll
  for (int qt = 0; qt < 2; qt++)
#pragma unroll
    for (int kc = 0; kc < 4; kc++)
      qf[qt][kc] = *(const bf16x8*)&Qp[(size_t)(qbase + qt * 16 + c) * 128 + kc * 32 + 8 * g];

  float sums[2] = {0.f, 0.f};   // per-lane: q column = qt*16 + c
  f32x4 hid[2][4];
#pragma unroll
  for (int qt = 0; qt < 2; qt++)
#pragma unroll
    for (int ct = 0; ct < 4; ct++) hid[qt][ct] = (f32x4){0.f, 0.f, 0.f, 0.f};
  short* myP = &PldsA[w * (32 * 40)];

  // ---- pass A: partial row sums + partial hidden over this wave's 1024-m half ----
  K_ISSUE(0); V_ISSUE(0);
  K_WRITE(0); V_WRITE(0);
  __syncthreads();
  for (int ch = 0; ch < 32; ch++) {
    const int buf = ch & 1;
    if (ch < 31) { K_ISSUE(ch + 1); V_ISSUE(ch + 1); }  // prefetch under compute

    const short* Kl = &KbufA[(half * 2 + buf) * (32 * 136)];
    const short* Vl = &VbufA[(half * 2 + buf) * (64 * 40)];
#pragma unroll
    for (int mt = 0; mt < 2; mt++) {
      bf16x8 kf[4];
#pragma unroll
      for (int kc = 0; kc < 4; kc++)
        kf[kc] = *(const bf16x8*)&Kl[(mt * 16 + c) * 136 + kc * 32 + 8 * g];
#pragma unroll
      for (int qt = 0; qt < 2; qt++) {
        // SWAPPED: D[m][q], m = mt*16 + 4g + j, q = qt*16 + c
        f32x4 s = {0.f, 0.f, 0.f, 0.f};
#pragma unroll
        for (int kc = 0; kc < 4; kc++)
          s = __builtin_amdgcn_mfma_f32_16x16x32_bf16(kf[kc], qf[qt][kc], s, 0, 0, 0);
        float p0 = fexp2(s[0] * SC), p1 = fexp2(s[1] * SC);
        float p2 = fexp2(s[2] * SC), p3 = fexp2(s[3] * SC);
        sums[qt] += (p0 + p1) + (p2 + p3);
        uint2 pk = {pk2(p0, p1), pk2(p2, p3)};
        *(uint2*)&myP[(qt * 16 + c) * 40 + mt * 16 + 4 * g] = pk;  // P[q][m], b64
      }
    }
    asm volatile("s_waitcnt lgkmcnt(0)" ::: "memory");  // P write->read handoff
    bf16x8 pf[2], vf[4];
#pragma unroll
    for (int qt = 0; qt < 2; qt++)
      pf[qt] = *(const bf16x8*)&myP[(qt * 16 + c) * 40 + 8 * g];
#pragma unroll
    for (int ct = 0; ct < 4; ct++)
      vf[ct] = *(const bf16x8*)&Vl[(ct * 16 + c) * 40 + 8 * g];
#pragma unroll
    for (int qt = 0; qt < 2; qt++)
#pragma unroll
      for (int ct = 0; ct < 4; ct++)
        hid[qt][ct] = __builtin_amdgcn_mfma_f32_16x16x32_bf16(pf[qt], vf[ct], hid[qt][ct], 0, 0, 0);

    if (ch < 31) { K_WRITE(buf ^ 1); V_WRITE(buf ^ 1); }
    __syncthreads();
  }

  // ---- in-block combine: sums via LDS; hidden partials via dead KbufA ----
#pragma unroll
  for (int qt = 0; qt < 2; qt++) {
    float s = sums[qt];
    s += __shfl_xor(s, 16);
    s += __shfl_xor(s, 32);
    if (g == 0) sums_lds[w * 32 + qt * 16 + c] = s;
  }
  float* hidx = (float*)pool;   // 32 KB scratch (KbufA region, dead here)
  if (half == 1) {
#pragma unroll
    for (int qt = 0; qt < 2; qt++)
#pragma unroll
      for (int ct = 0; ct < 4; ct++)
#pragma unroll
        for (int j = 0; j < 4; j++)
          hidx[(qw * 32 + qt * 16 + 4 * g + j) * 64 + ct * 16 + c] = hid[qt][ct][j];
  }
  __syncthreads();

  // hidden write (unswapped PV layout): q = qt*16 + 4g + j
  if (half == 0) {
#pragma unroll
    for (int qt = 0; qt < 2; qt++)
#pragma unroll
      for (int ct = 0; ct < 4; ct++)
#pragma unroll
        for (int j = 0; j < 4; j++) {
          int row = qt * 16 + 4 * g + j;
          float rcv = 1.0f / (sums_lds[qw * 32 + row] + sums_lds[(qw + 4) * 32 + row]);
          int q = qbase + row;
          float v = hid[qt][ct][j] + hidx[(qw * 32 + row) * 64 + ct * 16 + c];
          hidOut[((size_t)b * 2048 + q) * 512 + h * 64 + ct * 16 + c] = v * rcv;
        }
  }

  // recip for pass B's swapped layout: lane owns q = qt*16 + c (uniform in g)
  float rcB[2];
#pragma unroll
  for (int qt = 0; qt < 2; qt++)
    rcB[qt] = 1.0f / (sums_lds[qw * 32 + qt * 16 + c] + sums_lds[(qw + 4) * 32 + qt * 16 + c]);
  __syncthreads();  // hidx reads done before pass-B staging overwrites the pool

  // ---- pass B: staged K in 64-m chunks (Kbuf2 overlay), swapped MFMA, float4 stores ----
  K_ISSUE2(0); K_WRITE2(0);
  __syncthreads();
  for (int ch = 0; ch < 16; ch++) {
    const int buf = ch & 1;
    if (ch < 15) K_ISSUE2(ch + 1);

    const short* Kl = &pool[(half * 2 + buf) * (64 * 136)];
    const int mbase = m0 + ch * 64;
#pragma unroll
    for (int mt = 0; mt < 4; mt++) {
      bf16x8 kf[4];
#pragma unroll
      for (int kc = 0; kc < 4; kc++)
        kf[kc] = *(const bf16x8*)&Kl[(mt * 16 + c) * 136 + kc * 32 + 8 * g];
#pragma unroll
      for (int qt = 0; qt < 2; qt++) {
        // SWAPPED: D[m][q]; lane gets m = mt*16 + 4g + j for q = qt*16 + c
        f32x4 s = {0.f, 0.f, 0.f, 0.f};
#pragma unroll
        for (int kc = 0; kc < 4; kc++)
          s = __builtin_amdgcn_mfma_f32_16x16x32_bf16(kf[kc], qf[qt][kc], s, 0, 0, 0);
        float4 o = {fexp2(s[0] * SC) * rcB[qt], fexp2(s[1] * SC) * rcB[qt],
                    fexp2(s[2] * SC) * rcB[qt], fexp2(s[3] * SC) * rcB[qt]};
        *(float4*)&attnOut[((size_t)bh * 2048 + qbase + qt * 16 + c) * 2048
                           + mbase + mt * 16 + 4 * g] = o;
      }
    }

    if (ch < 15) K_WRITE2(buf ^ 1);
    __syncthreads();
  }
}

extern "C" void kernel_launch(void* const* d_in, const int* in_sizes, int n_in,
                              void* d_out, int out_size, void* d_ws, size_t ws_size,
                              hipStream_t stream) {
  const float* input_q = (const float*)d_in[0];
  const float* input_k = (const float*)d_in[1];
  const float* input_v = (const float*)d_in[2];
  const float* embed_q = (const float*)d_in[3];
  const float* embed_k = (const float*)d_in[4];
  const float* Wq = (const float*)d_in[5];
  const float* bq = (const float*)d_in[6];
  const float* Wk = (const float*)d_in[7];
  const float* bk = (const float*)d_in[8];
  const float* Wv = (const float*)d_in[9];
  const float* bv = (const float*)d_in[10];
  const float* Wp = (const float*)d_in[11];
  const float* bp = (const float*)d_in[12];

  // workspace layout (bf16 elements): QC 16MB | KC 16MB | VT 8MB | 4x WT 2MB  (~42MB)
  unsigned short* ws = (unsigned short*)d_ws;
  unsigned short* QC  = ws;
  unsigned short* KC  = QC + (size_t)32 * 2048 * 128;
  unsigned short* VT  = KC + (size_t)32 * 2048 * 128;
  unsigned short* WTq = VT + (size_t)32 * 64 * 2048;
  unsigned short* WTk = WTq + 512 * 512;
  unsigned short* WTv = WTk + 512 * 512;
  unsigned short* WTp = WTv + 512 * 512;

  wt_kernel<<<dim3(16, 16, 4), dim3(32, 8), 0, stream>>>(Wq, Wk, Wv, Wp, WTq, WTk, WTv, WTp);
  gemm_all<<<dim3(1280), 512, 0, stream>>>(input_q, embed_q, input_k, embed_k, input_v,
                                           WTq, WTk, WTp, WTv, bq, bk, bp, bv, QC, KC, VT);
  attn_kernel<<<dim3(512), 512, 0, stream>>>(QC, KC, VT, (float*)d_out);
}

// Round 17
// 279.284 us; speedup vs baseline: 1.0503x; 1.0123x over previous
//
#include <hip/hip_runtime.h>
#include <hip/hip_bf16.h>

typedef short bf16x8 __attribute__((ext_vector_type(8)));
typedef float f32x4 __attribute__((ext_vector_type(4)));

// B=4, N=M=2048, D=512, H=8, C=64; combined head dim = 128 (q|p, k|r)

__device__ __forceinline__ unsigned short f2bf(float f) {
  union { __hip_bfloat16 h; unsigned short u; } v;
  v.h = __float2bfloat16(f);
  return v.u;
}

__device__ __forceinline__ unsigned pk2(float a, float b) {
  union { __hip_bfloat162 h; unsigned u; } v;
  v.h = __float22bfloat162_rn(float2{a, b});
  return v.u;  // low 16 = bf16(a)
}

__device__ __forceinline__ float fexp2(float x) {
#if __has_builtin(__builtin_amdgcn_exp2f)
  return __builtin_amdgcn_exp2f(x);
#else
  return exp2f(x);
#endif
}

// ---------- weight transpose: W fp32 [K=512][D=512] -> WT bf16 [D][K] ----------
__global__ __launch_bounds__(256) void wt_kernel(
    const float* __restrict__ W0, const float* __restrict__ W1,
    const float* __restrict__ W2, const float* __restrict__ W3,
    unsigned short* __restrict__ T0, unsigned short* __restrict__ T1,
    unsigned short* __restrict__ T2, unsigned short* __restrict__ T3)
{
  __shared__ float t[32][33];
  const float* W; unsigned short* T;
  switch (blockIdx.z) {
    case 0: W = W0; T = T0; break;
    case 1: W = W1; T = T1; break;
    case 2: W = W2; T = T2; break;
    default: W = W3; T = T3; break;
  }
  int k0 = blockIdx.x * 32, d0 = blockIdx.y * 32;
  int tx = threadIdx.x, ty = threadIdx.y;
#pragma unroll
  for (int i = 0; i < 4; i++)
    t[ty + 8 * i][tx] = W[(size_t)(k0 + ty + 8 * i) * 512 + d0 + tx];
  __syncthreads();
#pragma unroll
  for (int i = 0; i < 4; i++)
    T[(size_t)(d0 + ty + 8 * i) * 512 + k0 + tx] = f2bf(t[tx][ty + 8 * i]);
}

// ---------- GEMM staging (512 threads): into LDS bf16 stride 72 (2-way free) ----------
__device__ __forceinline__ void stage64_f32(short* dst, const float* __restrict__ src,
                                            int row0, int kk, int tid) {
#pragma unroll
  for (int it = 0; it < 8; it++) {
    int idx = tid + 256 * it;           // 2048 float4s
    int r = idx >> 4, c4 = (idx & 15) << 2;
    float4 v = *(const float4*)&src[(size_t)(row0 + r) * 512 + kk + c4];
    uint2 pk = {pk2(v.x, v.y), pk2(v.z, v.w)};
    *(uint2*)&dst[r * 72 + c4] = pk;
  }
}

__device__ __forceinline__ void stage64_bf16(short* dst, const unsigned short* __restrict__ src,
                                             int row0, int kk, int tid) {
#pragma unroll
  for (int it = 0; it < 4; it++) {
    int idx = tid + 256 * it;           // 1024 ushort8s
    int r = idx >> 3, c8 = (idx & 7) << 3;
    bf16x8 v = *(const bf16x8*)&src[(size_t)(row0 + r) * 512 + kk + c8];
    *(bf16x8*)&dst[r * 72 + c8] = v;
  }
}

__device__ __forceinline__ void mfma_step64(const short* As, const short* Bs,
                                            f32x4 acc[4][4], int lane, int wr, int wc) {
  int rb = lane & 15, g8 = (lane >> 4) * 8;
#pragma unroll
  for (int ks = 0; ks < 64; ks += 32) {
    bf16x8 af[4], bfv[4];
#pragma unroll
    for (int t = 0; t < 4; t++) {
      af[t]  = *(const bf16x8*)&As[(wr * 64 + t * 16 + rb) * 72 + ks + g8];
      bfv[t] = *(const bf16x8*)&Bs[(wc * 64 + t * 16 + rb) * 72 + ks + g8];
    }
#pragma unroll
    for (int tm = 0; tm < 4; tm++)
#pragma unroll
      for (int tn = 0; tn < 4; tn++)
        acc[tm][tn] = __builtin_amdgcn_mfma_f32_16x16x32_bf16(af[tm], bfv[tn], acc[tm][tn], 0, 0, 0);
  }
}

// ---------- merged projections: z=0..3 Q/P/K/R (out QC/KC); z=4 V (out VT) ----------
__global__ __launch_bounds__(256) void gemm_all(
    const float* __restrict__ iq, const float* __restrict__ eq,
    const float* __restrict__ ik, const float* __restrict__ ek,
    const float* __restrict__ iv,
    const unsigned short* __restrict__ WTq, const unsigned short* __restrict__ WTk,
    const unsigned short* __restrict__ WTp, const unsigned short* __restrict__ WTv,
    const float* __restrict__ bq, const float* __restrict__ bk,
    const float* __restrict__ bp, const float* __restrict__ bv,
    unsigned short* __restrict__ QC, unsigned short* __restrict__ KC,
    unsigned short* __restrict__ VT)
{
  __shared__ short As[128 * 72];
  __shared__ short Bs[128 * 72];
  int tid = threadIdx.x, lane = tid & 63, w = tid >> 6;
  int wr = w >> 1, wc = w & 1;
  int g = lane >> 4, c = lane & 15;
  int z = blockIdx.z;
  f32x4 acc[4][4];
#pragma unroll
  for (int i = 0; i < 4; i++)
#pragma unroll
    for (int j = 0; j < 4; j++) acc[i][j] = (f32x4){0.f, 0.f, 0.f, 0.f};

  if (z < 4) {
    const float* A; const unsigned short* WT; const float* bias; unsigned short* out; int ooff;
    switch (z) {
      case 0: A = iq; WT = WTq; bias = bq; out = QC; ooff = 0;  break;
      case 1: A = eq; WT = WTp; bias = bp; out = QC; ooff = 64; break;
      case 2: A = ik; WT = WTk; bias = bk; out = KC; ooff = 0;  break;
      default: A = ek; WT = WTp; bias = bp; out = KC; ooff = 64; break;
    }
    int bi = blockIdx.y, bj = blockIdx.x;   // bj fastest -> A-tile L2 reuse
    for (int kk = 0; kk < 512; kk += 64) {
      __syncthreads();
      stage64_f32(As, A, bi * 128, kk, tid);
      stage64_bf16(Bs, WT, bj * 128, kk, tid);
      __syncthreads();
      mfma_step64(As, Bs, acc, lane, wr, wc);
    }
#pragma unroll
    for (int tm = 0; tm < 4; tm++) {
#pragma unroll
      for (int tn = 0; tn < 4; tn++) {
        int dcol = bj * 128 + wc * 64 + tn * 16 + c;
        float bvv = bias[dcol];
        int h = dcol >> 6, cc = dcol & 63;
#pragma unroll
        for (int j = 0; j < 4; j++) {
          int i = bi * 128 + wr * 64 + tm * 16 + 4 * g + j;  // global row = b*2048+n
          int b = i >> 11, n = i & 2047;
          out[((size_t)(b * 8 + h) * 2048 + n) * 128 + cc + ooff] = f2bf(acc[tm][tn][j] + bvv);
        }
      }
    }
  } else {
    // V projection, transposed output: VT[B][H][64][M]
    int bi = blockIdx.x, bj = blockIdx.y;   // x fastest: 4 d-tiles share one iv-tile
    for (int kk = 0; kk < 512; kk += 64) {
      __syncthreads();
      stage64_bf16(As, WTv, bi * 128, kk, tid);  // rows = d
      stage64_f32(Bs, iv, bj * 128, kk, tid);    // rows = s
      __syncthreads();
      mfma_step64(As, Bs, acc, lane, wr, wc);
    }
#pragma unroll
    for (int tm = 0; tm < 4; tm++) {
#pragma unroll
      for (int tn = 0; tn < 4; tn++) {
#pragma unroll
        for (int j = 0; j < 4; j++) {
          int i  = bi * 128 + wr * 64 + tm * 16 + 4 * g + j;  // d
          int jj = bj * 128 + wc * 64 + tn * 16 + c;          // s = b*2048+m
          int b = jj >> 11, m = jj & 2047;
          int h = i >> 6, cc = i & 63;
          VT[((size_t)(b * 8 + h) * 64 + cc) * 2048 + m] = f2bf(acc[tm][tn][j] + bv[i]);
        }
      }
    }
  }
}

// ---------- fused attention (R14, best measured 281.0 us) ----------
// pass A: K/V LDS-staged (32-m chunks), double-buffered; swapped QK^T; PV; combine.
// pass B: K LDS-staged in 64-m chunks (Kbuf2 aliases dead Vbuf/Plds) -> half the
//         barriers, 2x MFMA + 2x stores per round. sums_lds in non-overlapped tail.
__global__ __launch_bounds__(512, 4) void attn_kernel(
    const unsigned short* __restrict__ QC, const unsigned short* __restrict__ KC,
    const unsigned short* __restrict__ VT, float* __restrict__ out)
{
  // LDS pool (76800 B): [0) KbufA 34816 | [17408s) Vbuf 20480 | [27648s) Plds 20480 | [37888s) sums 1024
  // pass B: Kbuf2 = pool[0 .. 34816 shorts) = 69632 B (overlays KbufA+Vbuf+Plds; sums untouched)
  __shared__ __align__(16) short pool[38400];
  short* KbufA = pool;                      // [half][dbuf][32*136]
  short* VbufA = pool + 17408;              // [half][dbuf][64*40]
  short* PldsA = pool + 27648;              // [w][32*40]
  float* sums_lds = (float*)(pool + 37888); // [8][32]

  const int tid = threadIdx.x;
  const int lane = tid & 63, w = tid >> 6;
  const int g = lane >> 4, c = lane & 15;
  const int qw = w & 3, half = w >> 2;

  // XCD swizzle: 64 consecutive blocks (4 bh) per XCD -> K/V L2-resident
  const int lin = blockIdx.x;             // 512 blocks
  const int swz = (lin & 7) * 64 + (lin >> 3);
  const int qb = swz & 15, bh = swz >> 4;
  const int b = bh >> 3, h = bh & 7;

  const unsigned short* Qp = QC + (size_t)bh * 2048 * 128;
  const unsigned short* Kp = KC + (size_t)bh * 2048 * 128;
  const unsigned short* Vp = VT + (size_t)bh * 64 * 2048;
  float* hidOut = out;
  float* attnOut = out + (size_t)4 * 2048 * 512;

  const int qbase = qb * 128 + qw * 32;
  const int m0 = half * 1024;
  const float SC = 0.125f * 1.4426950408889634f;  // log2(e)/sqrt(C)

  // cooperative staging roles: 256 threads per half
  const int tt = tid & 255, sthalf = tid >> 8;
  const int krow = tt >> 3, ku = tt & 7;    // pass A K: 32 rows x 2x16B per thread
  const int vrow = tt >> 2, vu = tt & 3;    // pass A V: 64 rows x 1x16B per thread
  const int krow2 = tt >> 2, ku2 = tt & 3;  // pass B K: 64 rows x 4x16B per thread
  const int smb = sthalf * 1024;

  bf16x8 kr0, kr1, vr;
  auto K_ISSUE = [&](int ch) {
    const unsigned short* src = &Kp[(size_t)(smb + ch * 32 + krow) * 128];
    kr0 = *(const bf16x8*)&src[ku * 8];
    kr1 = *(const bf16x8*)&src[(ku + 8) * 8];
  };
  auto V_ISSUE = [&](int ch) {
    vr = *(const bf16x8*)&Vp[(size_t)vrow * 2048 + smb + ch * 32 + vu * 8];
  };
  auto K_WRITE = [&](int buf) {
    short* d = &KbufA[(sthalf * 2 + buf) * (32 * 136) + krow * 136];
    *(bf16x8*)&d[ku * 8] = kr0;
    *(bf16x8*)&d[(ku + 8) * 8] = kr1;
  };
  auto V_WRITE = [&](int buf) {
    *(bf16x8*)&VbufA[(sthalf * 2 + buf) * (64 * 40) + vrow * 40 + vu * 8] = vr;
  };

  bf16x8 kr2[4];
  auto K_ISSUE2 = [&](int ch) {
    const unsigned short* src = &Kp[(size_t)(smb + ch * 64 + krow2) * 128 + ku2 * 32];
#pragma unroll
    for (int i = 0; i < 4; i++) kr2[i] = *(const bf16x8*)&src[i * 8];
  };
  auto K_WRITE2 = [&](int buf) {
    short* d = &pool[(sthalf * 2 + buf) * (64 * 136) + krow2 * 136 + ku2 * 32];
#pragma unroll
    for (int i = 0; i < 4; i++) *(bf16x8*)&d[i * 8] = kr2[i];
  };

  // Q fragments resident for both passes (32 rows x 128 k)
  bf16x8 qf[2][4];
#pragma unroll
  for (int qt = 0; qt < 2; qt++)
#pragma unroll
    for (int kc = 0; kc < 4; kc++)
      qf[qt][kc] = *(const bf16x8*)&Qp[(size_t)(qbase + qt * 16 + c) * 128 + kc * 32 + 8 * g];

  float sums[2] = {0.f, 0.f};   // per-lane: q column = qt*16 + c
  f32x4 hid[2][4];
#pragma unroll
  for (int qt = 0; qt < 2; qt++)
#pragma unroll
    for (int ct = 0; ct < 4; ct++) hid[qt][ct] = (f32x4){0.f, 0.f, 0.f, 0.f};
  short* myP = &PldsA[w * (32 * 40)];

  // ---- pass A: partial row sums + partial hidden over this wave's 1024-m half ----
  K_ISSUE(0); V_ISSUE(0);
  K_WRITE(0); V_WRITE(0);
  __syncthreads();
  for (int ch = 0; ch < 32; ch++) {
    const int buf = ch & 1;
    if (ch < 31) { K_ISSUE(ch + 1); V_ISSUE(ch + 1); }  // prefetch under compute

    const short* Kl = &KbufA[(half * 2 + buf) * (32 * 136)];
    const short* Vl = &VbufA[(half * 2 + buf) * (64 * 40)];
#pragma unroll
    for (int mt = 0; mt < 2; mt++) {
      bf16x8 kf[4];
#pragma unroll
      for (int kc = 0; kc < 4; kc++)
        kf[kc] = *(const bf16x8*)&Kl[(mt * 16 + c) * 136 + kc * 32 + 8 * g];
#pragma unroll
      for (int qt = 0; qt < 2; qt++) {
        // SWAPPED: D[m][q], m = mt*16 + 4g + j, q = qt*16 + c
        f32x4 s = {0.f, 0.f, 0.f, 0.f};
#pragma unroll
        for (int kc = 0; kc < 4; kc++)
          s = __builtin_amdgcn_mfma_f32_16x16x32_bf16(kf[kc], qf[qt][kc], s, 0, 0, 0);
        float p0 = fexp2(s[0] * SC), p1 = fexp2(s[1] * SC);
        float p2 = fexp2(s[2] * SC), p3 = fexp2(s[3] * SC);
        sums[qt] += (p0 + p1) + (p2 + p3);
        uint2 pk = {pk2(p0, p1), pk2(p2, p3)};
        *(uint2*)&myP[(qt * 16 + c) * 40 + mt * 16 + 4 * g] = pk;  // P[q][m], b64
      }
    }
    asm volatile("s_waitcnt lgkmcnt(0)" ::: "memory");  // P write->read handoff
    bf16x8 pf[2], vf[4];
#pragma unroll
    for (int qt = 0; qt < 2; qt++)
      pf[qt] = *(const bf16x8*)&myP[(qt * 16 + c) * 40 + 8 * g];
#pragma unroll
    for (int ct = 0; ct < 4; ct++)
      vf[ct] = *(const bf16x8*)&Vl[(ct * 16 + c) * 40 + 8 * g];
#pragma unroll
    for (int qt = 0; qt < 2; qt++)
#pragma unroll
      for (int ct = 0; ct < 4; ct++)
        hid[qt][ct] = __builtin_amdgcn_mfma_f32_16x16x32_bf16(pf[qt], vf[ct], hid[qt][ct], 0, 0, 0);

    if (ch < 31) { K_WRITE(buf ^ 1); V_WRITE(buf ^ 1); }
    __syncthreads();
  }

  // ---- in-block combine: sums via LDS; hidden partials via dead KbufA ----
#pragma unroll
  for (int qt = 0; qt < 2; qt++) {
    float s = sums[qt];
    s += __shfl_xor(s, 16);
    s += __shfl_xor(s, 32);
    if (g == 0) sums_lds[w * 32 + qt * 16 + c] = s;
  }
  float* hidx = (float*)pool;   // 32 KB scratch (KbufA region, dead here)
  if (half == 1) {
#pragma unroll
    for (int qt = 0; qt < 2; qt++)
#pragma unroll
      for (int ct = 0; ct < 4; ct++)
#pragma unroll
        for (int j = 0; j < 4; j++)
          hidx[(qw * 32 + qt * 16 + 4 * g + j) * 64 + ct * 16 + c] = hid[qt][ct][j];
  }
  __syncthreads();

  // hidden write (unswapped PV layout): q = qt*16 + 4g + j
  if (half == 0) {
#pragma unroll
    for (int qt = 0; qt < 2; qt++)
#pragma unroll
      for (int ct = 0; ct < 4; ct++)
#pragma unroll
        for (int j = 0; j < 4; j++) {
          int row = qt * 16 + 4 * g + j;
          float rcv = 1.0f / (sums_lds[qw * 32 + row] + sums_lds[(qw + 4) * 32 + row]);
          int q = qbase + row;
          float v = hid[qt][ct][j] + hidx[(qw * 32 + row) * 64 + ct * 16 + c];
          hidOut[((size_t)b * 2048 + q) * 512 + h * 64 + ct * 16 + c] = v * rcv;
        }
  }

  // recip for pass B's swapped layout: lane owns q = qt*16 + c (uniform in g)
  float rcB[2];
#pragma unroll
  for (int qt = 0; qt < 2; qt++)
    rcB[qt] = 1.0f / (sums_lds[qw * 32 + qt * 16 + c] + sums_lds[(qw + 4) * 32 + qt * 16 + c]);
  __syncthreads();  // hidx reads done before pass-B staging overwrites the pool

  // ---- pass B: staged K in 64-m chunks (Kbuf2 overlay), swapped MFMA, float4 stores ----
  K_ISSUE2(0); K_WRITE2(0);
  __syncthreads();
  for (int ch = 0; ch < 16; ch++) {
    const int buf = ch & 1;
    if (ch < 15) K_ISSUE2(ch + 1);

    const short* Kl = &pool[(half * 2 + buf) * (64 * 136)];
    const int mbase = m0 + ch * 64;
#pragma unroll
    for (int mt = 0; mt < 4; mt++) {
      bf16x8 kf[4];
#pragma unroll
      for (int kc = 0; kc < 4; kc++)
        kf[kc] = *(const bf16x8*)&Kl[(mt * 16 + c) * 136 + kc * 32 + 8 * g];
#pragma unroll
      for (int qt = 0; qt < 2; qt++) {
        // SWAPPED: D[m][q]; lane gets m = mt*16 + 4g + j for q = qt*16 + c
        f32x4 s = {0.f, 0.f, 0.f, 0.f};
#pragma unroll
        for (int kc = 0; kc < 4; kc++)
          s = __builtin_amdgcn_mfma_f32_16x16x32_bf16(kf[kc], qf[qt][kc], s, 0, 0, 0);
        float4 o = {fexp2(s[0] * SC) * rcB[qt], fexp2(s[1] * SC) * rcB[qt],
                    fexp2(s[2] * SC) * rcB[qt], fexp2(s[3] * SC) * rcB[qt]};
        *(float4*)&attnOut[((size_t)bh * 2048 + qbase + qt * 16 + c) * 2048
                           + mbase + mt * 16 + 4 * g] = o;
      }
    }

    if (ch < 15) K_WRITE2(buf ^ 1);
    __syncthreads();
  }
}

extern "C" void kernel_launch(void* const* d_in, const int* in_sizes, int n_in,
                              void* d_out, int out_size, void* d_ws, size_t ws_size,
                              hipStream_t stream) {
  const float* input_q = (const float*)d_in[0];
  const float* input_k = (const float*)d_in[1];
  const float* input_v = (const float*)d_in[2];
  const float* embed_q = (const float*)d_in[3];
  const float* embed_k = (const float*)d_in[4];
  const float* Wq = (const float*)d_in[5];
  const float* bq = (const float*)d_in[6];
  const float* Wk = (const float*)d_in[7];
  const float* bk = (const float*)d_in[8];
  const float* Wv = (const float*)d_in[9];
  const float* bv = (const float*)d_in[10];
  const float* Wp = (const float*)d_in[11];
  const float* bp = (const float*)d_in[12];

  // workspace layout (bf16 elements): QC 16MB | KC 16MB | VT 8MB | 4x WT 2MB  (~42MB)
  unsigned short* ws = (unsigned short*)d_ws;
  unsigned short* QC  = ws;
  unsigned short* KC  = QC + (size_t)32 * 2048 * 128;
  unsigned short* VT  = KC + (size_t)32 * 2048 * 128;
  unsigned short* WTq = VT + (size_t)32 * 64 * 2048;
  unsigned short* WTk = WTq + 512 * 512;
  unsigned short* WTv = WTk + 512 * 512;
  unsigned short* WTp = WTv + 512 * 512;

  wt_kernel<<<dim3(16, 16, 4), dim3(32, 8), 0, stream>>>(Wq, Wk, Wv, Wp, WTq, WTk, WTv, WTp);
  gemm_all<<<dim3(4, 64, 5), 256, 0, stream>>>(input_q, embed_q, input_k, embed_k, input_v,
                                               WTq, WTk, WTp, WTv, bq, bk, bp, bv, QC, KC, VT);
  attn_kernel<<<dim3(512), 512, 0, stream>>>(QC, KC, VT, (float*)d_out);
}